// Round 3
// baseline (819.281 us; speedup 1.0000x reference)
//
#include <hip/hip_runtime.h>
#include <hip/hip_bf16.h>

typedef unsigned long long u64;

static constexpr int NF = 27552;              // 2*13776 faces
static constexpr int IMGOFF = 3 * 256 * 256;  // image elements before textures

#define EYEZ 2.7320508075688772f   // -(EYE.z) = 1/tan(30deg)+1, fp64->fp32

// ws layout (bytes):
//   keys : [0, 524288)            65536 u64 packed (zp_bits<<32)|orig_face_id
//   fcnt : [524288, 524292)       compacted front-face count
//   fdat : [524304, 2287632)      NF*16 f32, orig-indexed (epilogue)
//   cf   : [2287632, 4050960)     NF*16 f32, compacted front faces (hot loop)
//   cbb  : [4050960, 4491792)     NF float4, compacted bboxes
static constexpr size_t OFF_KEYS = 0;
static constexpr size_t OFF_FCNT = 524288;
static constexpr size_t OFF_FDAT = 524304;
static constexpr size_t OFF_CF   = 2287632;
static constexpr size_t OFF_CBB  = 4050960;

static constexpr u64 FARKEY = ((u64)0x42C80000u << 32);  // depth=100.0f, id 0

// ---------------------------------------------------------------------------
// Kernel 0: init keys to FAR and zero the compaction counter (ws is poisoned
// 0xAA before every timed launch).
// ---------------------------------------------------------------------------
__global__ __launch_bounds__(256) void init_ws(u64* __restrict__ keys,
                                               int* __restrict__ fcnt)
{
    int i = blockIdx.x * 256 + threadIdx.x;
    keys[i] = FARKEY;
    if (i == 0) *fcnt = 0;
}

// ---------------------------------------------------------------------------
// Kernel 1: per-face rasterization constants (orig-indexed, for epilogue)
// + compacted front-face list {a,b,c,ds,iz,id} + bbox for the hot loop.
// All fp ops replicate numpy's op order exactly (no FMA contraction) so the
// per-pixel depth argmin is bit-identical to the fp32 reference.
// fdat[f*16]: a0,a1,a2,b0,b1,b2,c0,c1,c2,det_safe,iz0,iz1,iz2,z0,z1,z2
// cf[p*16]:   a0,a1,a2,b0,b1,b2,c0,c1,c2,det_safe,iz0,iz1,iz2,idbits,-,-
// ---------------------------------------------------------------------------
__global__ __launch_bounds__(256) void face_prep(
    const float* __restrict__ cam,
    const float* __restrict__ verts,
    const int* __restrict__ faces,
    float* __restrict__ fdat,
    float* __restrict__ cf,
    float4* __restrict__ cbb,
    int* __restrict__ fcnt)
{
    int f = blockIdx.x * 256 + threadIdx.x;
    if (f >= NF) return;
    float c0 = cam[0], c1 = cam[1], c2 = cam[2];
    // replicate np look_at rounding exactly (these are 1.0 in binary FP, free)
    float z3 = __fdiv_rn(EYEZ, __fsqrt_rn(__fmul_rn(EYEZ, EYEZ)));
    float x0r = __fdiv_rn(z3, __fsqrt_rn(__fmul_rn(z3, z3)));
    float wyy = __fmul_rn(z3, x0r);
    float y1r = __fdiv_rn(wyy, __fsqrt_rn(__fmul_rn(wyy, wyy)));

    float xs[3], ys[3], zs[3];
#pragma unroll
    for (int i = 0; i < 3; i++) {
        int vi = faces[f * 3 + i];
        float vx = verts[vi * 3 + 0];
        float vy = verts[vi * 3 + 1];
        float vz = verts[vi * 3 + 2];
        float px = __fmul_rn(c0, __fadd_rn(vx, c1));
        float py = __fmul_rn(c0, __fadd_rn(vy, c2));
        xs[i] = __fmul_rn(px, x0r);
        ys[i] = __fmul_rn(-py, y1r);
        zs[i] = __fmul_rn(__fadd_rn(vz, EYEZ), z3);
    }
    float a0 = __fsub_rn(ys[1], ys[2]);
    float a1 = __fsub_rn(ys[2], ys[0]);
    float a2 = __fsub_rn(ys[0], ys[1]);
    float b0 = __fsub_rn(xs[2], xs[1]);
    float b1 = __fsub_rn(xs[0], xs[2]);
    float b2 = __fsub_rn(xs[1], xs[0]);
    float cc0 = __fsub_rn(__fmul_rn(xs[1], ys[2]), __fmul_rn(xs[2], ys[1]));
    float cc1 = __fsub_rn(__fmul_rn(xs[2], ys[0]), __fmul_rn(xs[0], ys[2]));
    float cc2 = __fsub_rn(__fmul_rn(xs[0], ys[1]), __fmul_rn(xs[1], ys[0]));
    float det = __fadd_rn(__fadd_rn(cc0, cc1), cc2);
    float ds  = (fabsf(det) > 1e-10f) ? det : 1e-10f;
    float z0 = (fabsf(zs[0]) > 1e-6f) ? zs[0] : 1e-6f;
    float z1 = (fabsf(zs[1]) > 1e-6f) ? zs[1] : 1e-6f;
    float z2 = (fabsf(zs[2]) > 1e-6f) ? zs[2] : 1e-6f;
    float iz0 = __fdiv_rn(1.0f, z0);
    float iz1 = __fdiv_rn(1.0f, z1);
    float iz2 = __fdiv_rn(1.0f, z2);

    float* o = fdat + (size_t)f * 16;
    o[0] = a0; o[1] = a1; o[2] = a2;
    o[3] = b0; o[4] = b1; o[5] = b2;
    o[6] = cc0; o[7] = cc1; o[8] = cc2;
    o[9] = ds;
    o[10] = iz0; o[11] = iz1; o[12] = iz2;
    o[13] = z0; o[14] = z1; o[15] = z2;

    if (det > 0.0f) {   // back faces can never be `valid` -> exact cull
        int pos = atomicAdd(fcnt, 1);
        float* q = cf + (size_t)pos * 16;
        q[0] = a0; q[1] = a1; q[2] = a2;
        q[3] = b0; q[4] = b1; q[5] = b2;
        q[6] = cc0; q[7] = cc1; q[8] = cc2;
        q[9] = ds;
        q[10] = iz0; q[11] = iz1; q[12] = iz2;
        q[13] = __int_as_float(f);
        q[14] = 0.0f; q[15] = 0.0f;
        float4 bb;
        bb.x = fminf(fminf(xs[0], xs[1]), xs[2]) - 1e-4f;
        bb.y = fmaxf(fmaxf(xs[0], xs[1]), xs[2]) + 1e-4f;
        bb.z = fminf(fminf(ys[0], ys[1]), ys[2]) - 1e-4f;
        bb.w = fmaxf(fmaxf(ys[0], ys[1]), ys[2]) + 1e-4f;
        cbb[pos] = bb;
    }
}

// ---------------------------------------------------------------------------
// Kernel 2: 9 bilinear texture samples per face -> textures output (fp32).
// lighting() is the identity (DIR_INT=0, AMB=1).  3rd TS dim is broadcast.
// ---------------------------------------------------------------------------
__global__ __launch_bounds__(256) void tex_sample(
    const float* __restrict__ cam,
    const float* __restrict__ verts,
    const int* __restrict__ faces,
    const float* __restrict__ uv,
    float* __restrict__ out_tex)
{
    int id = blockIdx.x * 256 + threadIdx.x;
    if (id >= NF * 9) return;
    int f = id / 9, t = id - f * 9;
    float c0 = cam[0], c1 = cam[1], c2 = cam[2];
    float px[3], py[3];
#pragma unroll
    for (int i = 0; i < 3; i++) {
        int vi = faces[f * 3 + i];
        px[i] = __fmul_rn(c0, __fadd_rn(verts[vi * 3 + 0], c1));
        py[i] = __fmul_rn(c0, __fadd_rn(verts[vi * 3 + 1], c2));
    }
    const float abv[3] = {0.0f, 0.5f, 1.0f};
    int t1 = t / 3, t2 = t - t1 * 3;
    float uu = abv[t1], vv = abv[t2];
    float sx = __fadd_rn(__fadd_rn(__fmul_rn(__fsub_rn(px[0], px[2]), uu),
                                   __fmul_rn(__fsub_rn(px[1], px[2]), vv)), px[2]);
    float sy = __fadd_rn(__fadd_rn(__fmul_rn(__fsub_rn(py[0], py[2]), uu),
                                   __fmul_rn(__fsub_rn(py[1], py[2]), vv)), py[2]);
    sx = fminf(fmaxf(sx, -1.0f), 1.0f);
    sy = fminf(fmaxf(sy, -1.0f), 1.0f);
    float xg = __fmul_rn(__fmul_rn(__fadd_rn(sx, 1.0f), 0.5f), 255.0f);
    float yg = __fmul_rn(__fmul_rn(__fadd_rn(sy, 1.0f), 0.5f), 255.0f);
    float x0f = floorf(xg), y0f = floorf(yg);
    float wx = __fsub_rn(xg, x0f), wy = __fsub_rn(yg, y0f);
    int x0 = (int)x0f; x0 = x0 < 0 ? 0 : (x0 > 255 ? 255 : x0);
    int y0 = (int)y0f; y0 = y0 < 0 ? 0 : (y0 > 255 ? 255 : y0);
    int x1 = x0 + 1 > 255 ? 255 : x0 + 1;
    int y1 = y0 + 1 > 255 ? 255 : y0 + 1;
    float omwx = __fsub_rn(1.0f, wx), omwy = __fsub_rn(1.0f, wy);
    float w00 = __fmul_rn(omwx, omwy);
    float w10 = __fmul_rn(wx, omwy);
    float w01 = __fmul_rn(omwx, wy);
    float w11 = __fmul_rn(wx, wy);
    size_t tb = (size_t)f * 81 + (size_t)t1 * 27 + (size_t)t2 * 9;
#pragma unroll
    for (int c = 0; c < 3; c++) {
        const float* img = uv + c * 65536;
        float g00 = img[y0 * 256 + x0];
        float g10 = img[y0 * 256 + x1];
        float g01 = img[y1 * 256 + x0];
        float g11 = img[y1 * 256 + x1];
        float val = __fmul_rn(g00, w00);
        val = __fadd_rn(val, __fmul_rn(g10, w10));
        val = __fadd_rn(val, __fmul_rn(g01, w01));
        val = __fadd_rn(val, __fmul_rn(g11, w11));
        out_tex[tb + 0 + c] = val;   // k = 0,1,2 broadcast
        out_tex[tb + 3 + c] = val;
        out_tex[tb + 6 + c] = val;
    }
}

// ---------------------------------------------------------------------------
// Kernel 3: depth argmin. Each WAVE owns one (8x8-pixel tile, face-slice)
// pair: lane = pixel, faces iterated wave-uniformly via ballot compaction.
// No barriers, no LDS. Partial winners merge via global u64 atomicMin
// (order-independent -> deterministic across graph replays).
// Key = (zp_bits<<32)|orig_id: bit-exact numpy depth + first-index ties.
// ---------------------------------------------------------------------------
__global__ __launch_bounds__(256, 8) void raster_min(
    const float* __restrict__ cf,
    const float4* __restrict__ cbb,
    const int* __restrict__ fcnt,
    u64* __restrict__ keys)
{
    const int lane = threadIdx.x & 63;
    const int gw = blockIdx.x * 4 + (threadIdx.x >> 6);  // 0..8191
    const int tile = gw & 1023;                          // 32x32 tiles
    const int slice = gw >> 10;                          // 8 face-slices
    const int tx = tile & 31, ty = tile >> 5;
    const int pxi = tx * 8 + (lane & 7), pyi = ty * 8 + (lane >> 3);
    const float xp = (float)(2 * pxi + 1 - 256) * (1.0f / 256.0f);  // exact
    const float yp = (float)(2 * pyi + 1 - 256) * (1.0f / 256.0f);
    const float xlo = (float)(2 * (tx * 8) + 1 - 256) * (1.0f / 256.0f);
    const float xhi = (float)(2 * (tx * 8 + 7) + 1 - 256) * (1.0f / 256.0f);
    const float ylo = (float)(2 * (ty * 8) + 1 - 256) * (1.0f / 256.0f);
    const float yhi = (float)(2 * (ty * 8 + 7) + 1 - 256) * (1.0f / 256.0f);

    const int n = *fcnt;
    const int per = (n + 7) >> 3;
    const int s0 = slice * per;
    const int s1 = (s0 + per < n) ? s0 + per : n;

    u64 best = FARKEY;

    for (int cb = s0; cb < s1; cb += 64) {
        int fi = cb + lane;
        bool p = false;
        if (fi < s1) {
            float4 bb = cbb[fi];
            p = (bb.x <= xhi) && (bb.y >= xlo) && (bb.z <= yhi) && (bb.w >= ylo);
        }
        u64 m = __ballot(p);
        while (m) {
            int j = __builtin_ctzll(m);
            m &= m - 1;
            const float4* fq = (const float4*)(cf + (size_t)(cb + j) * 16);
            float4 q0 = fq[0], q1 = fq[1], q2 = fq[2], q3 = fq[3];
            float t0 = __fadd_rn(__fadd_rn(__fmul_rn(xp, q0.x), __fmul_rn(yp, q0.w)), q1.z);
            float t1 = __fadd_rn(__fadd_rn(__fmul_rn(xp, q0.y), __fmul_rn(yp, q1.x)), q1.w);
            float t2 = __fadd_rn(__fadd_rn(__fmul_rn(xp, q0.z), __fmul_rn(yp, q1.y)), q2.x);
            // staged faces have ds>0 => sign(w)==sign(t): exact w>=0 test
            bool in = !(t0 < 0.0f) && !(t1 < 0.0f) && !(t2 < 0.0f);
            if (!__any(in)) continue;
            float ds = q2.y;
            float w0 = __fdiv_rn(t0, ds);
            float w1 = __fdiv_rn(t1, ds);
            float w2 = __fdiv_rn(t2, ds);
            in = in && !(w0 > 1.0f) && !(w1 > 1.0f) && !(w2 > 1.0f);
            float den = __fmul_rn(w0, q2.z);
            den = __fadd_rn(den, __fmul_rn(w1, q2.w));
            den = __fadd_rn(den, __fmul_rn(w2, q3.x));
            if (in && den > 1e-8f) {
                float zp = __fdiv_rn(1.0f, den);
                if (zp > 0.1f && zp < 100.0f) {
                    u64 key = ((u64)__float_as_uint(zp) << 32)
                            | (u64)(unsigned)__float_as_int(q3.y);
                    if (key < best) best = key;
                }
            }
        }
    }
    atomicMin(&keys[(size_t)pyi * 256 + pxi], best);
}

// ---------------------------------------------------------------------------
// Kernel 4: per-pixel epilogue — recompute exact barycentrics for the winner
// and trilinear-sample the face texture (numpy op order, bit-exact path).
// ---------------------------------------------------------------------------
__global__ __launch_bounds__(256) void epilogue(
    const u64* __restrict__ keys,
    const float* __restrict__ fdat,
    const float* __restrict__ tex,   // d_out + IMGOFF, from tex_sample
    float* __restrict__ out_img)
{
    int pix = blockIdx.x * 256 + threadIdx.x;   // 65536
    int xo = pix & 255, yo = pix >> 8;
    const float xp = (float)(2 * xo + 1 - 256) * (1.0f / 256.0f);
    const float yp = (float)(2 * yo + 1 - 256) * (1.0f / 256.0f);
    u64 m = keys[pix];
    float depth = __uint_as_float((unsigned)(m >> 32));
    float col0 = 0.f, col1 = 0.f, col2 = 0.f;
    if (depth < 100.0f) {
        int fidx = (int)(unsigned)(m & 0xFFFFFFFFu);
        const float* fd = fdat + (size_t)fidx * 16;
        float t0 = __fadd_rn(__fadd_rn(__fmul_rn(xp, fd[0]), __fmul_rn(yp, fd[3])), fd[6]);
        float t1 = __fadd_rn(__fadd_rn(__fmul_rn(xp, fd[1]), __fmul_rn(yp, fd[4])), fd[7]);
        float t2 = __fadd_rn(__fadd_rn(__fmul_rn(xp, fd[2]), __fmul_rn(yp, fd[5])), fd[8]);
        float dsf = fd[9];
        float w0 = __fdiv_rn(t0, dsf), w1 = __fdiv_rn(t1, dsf), w2 = __fdiv_rn(t2, dsf);
        float wc0 = __fdiv_rn(w0, fd[13]);
        float wc1 = __fdiv_rn(w1, fd[14]);
        float wc2 = __fdiv_rn(w2, fd[15]);
        float ssum = __fadd_rn(__fadd_rn(wc0, wc1), wc2);
        float dnm = fmaxf(ssum, 1e-8f);
        wc0 = __fdiv_rn(wc0, dnm); wc1 = __fdiv_rn(wc1, dnm); wc2 = __fdiv_rn(wc2, dnm);
        float pos0 = __fmul_rn(fminf(fmaxf(wc0, 0.f), 1.f), 2.0f);
        float pos1 = __fmul_rn(fminf(fmaxf(wc1, 0.f), 1.f), 2.0f);
        float pos2 = __fmul_rn(fminf(fmaxf(wc2, 0.f), 1.f), 2.0f);
        float lf0 = fminf(fmaxf(floorf(pos0), 0.f), 2.f);
        float lf1 = fminf(fmaxf(floorf(pos1), 0.f), 2.f);
        float lf2 = fminf(fmaxf(floorf(pos2), 0.f), 2.f);
        float fr0 = __fsub_rn(pos0, lf0), fr1 = __fsub_rn(pos1, lf1), fr2 = __fsub_rn(pos2, lf2);
        int lo0 = (int)lf0, lo1 = (int)lf1;
        int hi0 = lo0 + 1 > 2 ? 2 : lo0 + 1;
        int hi1 = lo1 + 1 > 2 ? 2 : lo1 + 1;
        const float* tbase = tex + (size_t)fidx * 81;
#pragma unroll
        for (int bits = 0; bits < 8; bits++) {
            int u0 = bits & 1, u1 = (bits >> 1) & 1, u2 = (bits >> 2) & 1;
            int i0 = u0 ? hi0 : lo0;
            int i1 = u1 ? hi1 : lo1;
            float e0 = u0 ? fr0 : __fsub_rn(1.0f, fr0);
            float e1 = u1 ? fr1 : __fsub_rn(1.0f, fr1);
            float e2 = u2 ? fr2 : __fsub_rn(1.0f, fr2);
            float wgt = __fmul_rn(__fmul_rn(e0, e1), e2);
            const float* tp = tbase + (size_t)i0 * 27 + (size_t)i1 * 9;  // k broadcast
            col0 = __fadd_rn(col0, __fmul_rn(wgt, tp[0]));
            col1 = __fadd_rn(col1, __fmul_rn(wgt, tp[1]));
            col2 = __fadd_rn(col2, __fmul_rn(wgt, tp[2]));
        }
    }
    out_img[pix]          = col0;
    out_img[65536 + pix]  = col1;
    out_img[131072 + pix] = col2;
}

extern "C" void kernel_launch(void* const* d_in, const int* in_sizes, int n_in,
                              void* d_out, int out_size, void* d_ws, size_t ws_size,
                              hipStream_t stream) {
    const float* cam   = (const float*)d_in[0];
    const float* verts = (const float*)d_in[1];
    const float* uv    = (const float*)d_in[2];
    const int*   faces = (const int*)d_in[3];
    float* out = (float*)d_out;

    char* ws = (char*)d_ws;
    u64*    keys = (u64*)(ws + OFF_KEYS);
    int*    fcnt = (int*)(ws + OFF_FCNT);
    float*  fdat = (float*)(ws + OFF_FDAT);
    float*  cf   = (float*)(ws + OFF_CF);
    float4* cbb  = (float4*)(ws + OFF_CBB);

    float* out_img = out;            // 3*256*256
    float* out_tex = out + IMGOFF;   // NF*81

    hipLaunchKernelGGL(init_ws, dim3(256), dim3(256), 0, stream, keys, fcnt);
    hipLaunchKernelGGL(face_prep, dim3((NF + 255) / 256), dim3(256), 0, stream,
                       cam, verts, faces, fdat, cf, cbb, fcnt);
    hipLaunchKernelGGL(tex_sample, dim3((NF * 9 + 255) / 256), dim3(256), 0, stream,
                       cam, verts, faces, uv, out_tex);
    hipLaunchKernelGGL(raster_min, dim3(2048), dim3(256), 0, stream,
                       cf, cbb, fcnt, keys);
    hipLaunchKernelGGL(epilogue, dim3(256), dim3(256), 0, stream,
                       keys, fdat, out_tex, out_img);
}

// Round 4
// 408.807 us; speedup vs baseline: 2.0041x; 2.0041x over previous
//
#include <hip/hip_runtime.h>
#include <hip/hip_bf16.h>

typedef unsigned long long u64;

static constexpr int NF = 27552;              // 2*13776 faces
static constexpr int IMGOFF = 3 * 256 * 256;  // image elements before textures
static constexpr int NSLICE = 16;             // face-slices per tile

#define EYEZ 2.7320508075688772f   // -(EYE.z) = 1/tan(30deg)+1, fp64->fp32

// ws layout (bytes):
//   keys : [0, 524288)            65536 u64 packed (zp_bits<<32)|orig_face_id
//   fcnt : [524288, 524292)       compacted front-face count
//   fdat : [524304, 2287632)      NF*16 f32, orig-indexed (epilogue)
//   cf   : [2287632, 4050960)     NF*16 f32, compacted front faces (hot loop)
//   cbb  : [4050960, 4491792)     NF float4, compacted bboxes
static constexpr size_t OFF_KEYS = 0;
static constexpr size_t OFF_FCNT = 524288;
static constexpr size_t OFF_FDAT = 524304;
static constexpr size_t OFF_CF   = 2287632;
static constexpr size_t OFF_CBB  = 4050960;

static constexpr u64 FARKEY = ((u64)0x42C80000u << 32);  // depth=100.0f, id 0

// ---------------------------------------------------------------------------
// Kernel 0: init keys to FAR and zero the compaction counter.
// ---------------------------------------------------------------------------
__global__ __launch_bounds__(256) void init_ws(u64* __restrict__ keys,
                                               int* __restrict__ fcnt)
{
    int i = blockIdx.x * 256 + threadIdx.x;
    keys[i] = FARKEY;
    if (i == 0) *fcnt = 0;
}

// ---------------------------------------------------------------------------
// Kernel 1: per-face rasterization constants (orig-indexed, for epilogue)
// + compacted front-face list {a,b,c,ds,iz,id} + bbox for the hot loop.
// All fp ops replicate numpy's op order exactly (no FMA contraction) so the
// per-pixel depth argmin is bit-identical to the fp32 reference.
// fdat[f*16]: a0,a1,a2,b0,b1,b2,c0,c1,c2,det_safe,iz0,iz1,iz2,z0,z1,z2
// cf[p*16]:   a0,a1,a2,b0,b1,b2,c0,c1,c2,det_safe,iz0,iz1,iz2,idbits,-,-
// ---------------------------------------------------------------------------
__global__ __launch_bounds__(256) void face_prep(
    const float* __restrict__ cam,
    const float* __restrict__ verts,
    const int* __restrict__ faces,
    float* __restrict__ fdat,
    float* __restrict__ cf,
    float4* __restrict__ cbb,
    int* __restrict__ fcnt)
{
    int f = blockIdx.x * 256 + threadIdx.x;
    if (f >= NF) return;
    float c0 = cam[0], c1 = cam[1], c2 = cam[2];
    // replicate np look_at rounding exactly (these are 1.0 in binary FP, free)
    float z3 = __fdiv_rn(EYEZ, __fsqrt_rn(__fmul_rn(EYEZ, EYEZ)));
    float x0r = __fdiv_rn(z3, __fsqrt_rn(__fmul_rn(z3, z3)));
    float wyy = __fmul_rn(z3, x0r);
    float y1r = __fdiv_rn(wyy, __fsqrt_rn(__fmul_rn(wyy, wyy)));

    float xs[3], ys[3], zs[3];
#pragma unroll
    for (int i = 0; i < 3; i++) {
        int vi = faces[f * 3 + i];
        float vx = verts[vi * 3 + 0];
        float vy = verts[vi * 3 + 1];
        float vz = verts[vi * 3 + 2];
        float px = __fmul_rn(c0, __fadd_rn(vx, c1));
        float py = __fmul_rn(c0, __fadd_rn(vy, c2));
        xs[i] = __fmul_rn(px, x0r);
        ys[i] = __fmul_rn(-py, y1r);
        zs[i] = __fmul_rn(__fadd_rn(vz, EYEZ), z3);
    }
    float a0 = __fsub_rn(ys[1], ys[2]);
    float a1 = __fsub_rn(ys[2], ys[0]);
    float a2 = __fsub_rn(ys[0], ys[1]);
    float b0 = __fsub_rn(xs[2], xs[1]);
    float b1 = __fsub_rn(xs[0], xs[2]);
    float b2 = __fsub_rn(xs[1], xs[0]);
    float cc0 = __fsub_rn(__fmul_rn(xs[1], ys[2]), __fmul_rn(xs[2], ys[1]));
    float cc1 = __fsub_rn(__fmul_rn(xs[2], ys[0]), __fmul_rn(xs[0], ys[2]));
    float cc2 = __fsub_rn(__fmul_rn(xs[0], ys[1]), __fmul_rn(xs[1], ys[0]));
    float det = __fadd_rn(__fadd_rn(cc0, cc1), cc2);
    float ds  = (fabsf(det) > 1e-10f) ? det : 1e-10f;
    float z0 = (fabsf(zs[0]) > 1e-6f) ? zs[0] : 1e-6f;
    float z1 = (fabsf(zs[1]) > 1e-6f) ? zs[1] : 1e-6f;
    float z2 = (fabsf(zs[2]) > 1e-6f) ? zs[2] : 1e-6f;
    float iz0 = __fdiv_rn(1.0f, z0);
    float iz1 = __fdiv_rn(1.0f, z1);
    float iz2 = __fdiv_rn(1.0f, z2);

    float* o = fdat + (size_t)f * 16;
    o[0] = a0; o[1] = a1; o[2] = a2;
    o[3] = b0; o[4] = b1; o[5] = b2;
    o[6] = cc0; o[7] = cc1; o[8] = cc2;
    o[9] = ds;
    o[10] = iz0; o[11] = iz1; o[12] = iz2;
    o[13] = z0; o[14] = z1; o[15] = z2;

    if (det > 0.0f) {   // back faces can never be `valid` -> exact cull
        int pos = atomicAdd(fcnt, 1);
        float* q = cf + (size_t)pos * 16;
        q[0] = a0; q[1] = a1; q[2] = a2;
        q[3] = b0; q[4] = b1; q[5] = b2;
        q[6] = cc0; q[7] = cc1; q[8] = cc2;
        q[9] = ds;
        q[10] = iz0; q[11] = iz1; q[12] = iz2;
        q[13] = __int_as_float(f);
        q[14] = 0.0f; q[15] = 0.0f;
        float4 bb;
        bb.x = fminf(fminf(xs[0], xs[1]), xs[2]) - 1e-4f;
        bb.y = fmaxf(fmaxf(xs[0], xs[1]), xs[2]) + 1e-4f;
        bb.z = fminf(fminf(ys[0], ys[1]), ys[2]) - 1e-4f;
        bb.w = fmaxf(fmaxf(ys[0], ys[1]), ys[2]) + 1e-4f;
        cbb[pos] = bb;
    }
}

// ---------------------------------------------------------------------------
// Kernel 2: 9 bilinear texture samples per face -> textures output (fp32).
// lighting() is the identity (DIR_INT=0, AMB=1).  3rd TS dim is broadcast.
// ---------------------------------------------------------------------------
__global__ __launch_bounds__(256) void tex_sample(
    const float* __restrict__ cam,
    const float* __restrict__ verts,
    const int* __restrict__ faces,
    const float* __restrict__ uv,
    float* __restrict__ out_tex)
{
    int id = blockIdx.x * 256 + threadIdx.x;
    if (id >= NF * 9) return;
    int f = id / 9, t = id - f * 9;
    float c0 = cam[0], c1 = cam[1], c2 = cam[2];
    float px[3], py[3];
#pragma unroll
    for (int i = 0; i < 3; i++) {
        int vi = faces[f * 3 + i];
        px[i] = __fmul_rn(c0, __fadd_rn(verts[vi * 3 + 0], c1));
        py[i] = __fmul_rn(c0, __fadd_rn(verts[vi * 3 + 1], c2));
    }
    const float abv[3] = {0.0f, 0.5f, 1.0f};
    int t1 = t / 3, t2 = t - t1 * 3;
    float uu = abv[t1], vv = abv[t2];
    float sx = __fadd_rn(__fadd_rn(__fmul_rn(__fsub_rn(px[0], px[2]), uu),
                                   __fmul_rn(__fsub_rn(px[1], px[2]), vv)), px[2]);
    float sy = __fadd_rn(__fadd_rn(__fmul_rn(__fsub_rn(py[0], py[2]), uu),
                                   __fmul_rn(__fsub_rn(py[1], py[2]), vv)), py[2]);
    sx = fminf(fmaxf(sx, -1.0f), 1.0f);
    sy = fminf(fmaxf(sy, -1.0f), 1.0f);
    float xg = __fmul_rn(__fmul_rn(__fadd_rn(sx, 1.0f), 0.5f), 255.0f);
    float yg = __fmul_rn(__fmul_rn(__fadd_rn(sy, 1.0f), 0.5f), 255.0f);
    float x0f = floorf(xg), y0f = floorf(yg);
    float wx = __fsub_rn(xg, x0f), wy = __fsub_rn(yg, y0f);
    int x0 = (int)x0f; x0 = x0 < 0 ? 0 : (x0 > 255 ? 255 : x0);
    int y0 = (int)y0f; y0 = y0 < 0 ? 0 : (y0 > 255 ? 255 : y0);
    int x1 = x0 + 1 > 255 ? 255 : x0 + 1;
    int y1 = y0 + 1 > 255 ? 255 : y0 + 1;
    float omwx = __fsub_rn(1.0f, wx), omwy = __fsub_rn(1.0f, wy);
    float w00 = __fmul_rn(omwx, omwy);
    float w10 = __fmul_rn(wx, omwy);
    float w01 = __fmul_rn(omwx, wy);
    float w11 = __fmul_rn(wx, wy);
    size_t tb = (size_t)f * 81 + (size_t)t1 * 27 + (size_t)t2 * 9;
#pragma unroll
    for (int c = 0; c < 3; c++) {
        const float* img = uv + c * 65536;
        float g00 = img[y0 * 256 + x0];
        float g10 = img[y0 * 256 + x1];
        float g01 = img[y1 * 256 + x0];
        float g11 = img[y1 * 256 + x1];
        float val = __fmul_rn(g00, w00);
        val = __fadd_rn(val, __fmul_rn(g10, w10));
        val = __fadd_rn(val, __fmul_rn(g01, w01));
        val = __fadd_rn(val, __fmul_rn(g11, w11));
        out_tex[tb + 0 + c] = val;   // k = 0,1,2 broadcast
        out_tex[tb + 3 + c] = val;
        out_tex[tb + 6 + c] = val;
    }
}

// ---------------------------------------------------------------------------
// Kernel 3: depth argmin. Wave = (8x8 tile, face-slice). Per 64-face chunk:
// lane loads one face (coalesced), exact triangle-vs-tile SAT cull (bbox
// axes + 3 edge axes, conservative margins), ballot+prefix-sum compaction
// into the wave's private LDS region (no barriers: intra-wave DS is
// in-order), next chunk prefetched before the inner loop. Inner loop reads
// wave-uniform ds_read_b128 (broadcast) and runs the bit-exact numpy path.
// Winner key = (zp_bits<<32)|orig_id, merged via global atomicMin.
// ---------------------------------------------------------------------------
__global__ __launch_bounds__(256, 8) void raster_min(
    const float* __restrict__ cf,
    const float4* __restrict__ cbb,
    const int* __restrict__ fcnt,
    u64* __restrict__ keys)
{
    __shared__ __align__(16) float sface[4][64 * 16];   // 4 KB per wave
    const int lane = threadIdx.x & 63;
    const int wid  = threadIdx.x >> 6;
    const int gw = blockIdx.x * 4 + wid;                // 0..16383
    const int tile = gw & 1023;                         // 32x32 tiles
    const int slice = gw >> 10;                         // 16 face-slices
    const int tx = tile & 31, ty = tile >> 5;
    const int pxi = tx * 8 + (lane & 7), pyi = ty * 8 + (lane >> 3);
    const float xp = (float)(2 * pxi + 1 - 256) * (1.0f / 256.0f);  // exact
    const float yp = (float)(2 * pyi + 1 - 256) * (1.0f / 256.0f);
    const float xlo = (float)(2 * (tx * 8) + 1 - 256) * (1.0f / 256.0f);
    const float xhi = (float)(2 * (tx * 8 + 7) + 1 - 256) * (1.0f / 256.0f);
    const float ylo = (float)(2 * (ty * 8) + 1 - 256) * (1.0f / 256.0f);
    const float yhi = (float)(2 * (ty * 8 + 7) + 1 - 256) * (1.0f / 256.0f);
    float* sf = sface[wid];

    const int n = *fcnt;
    const int per = (n + NSLICE - 1) / NSLICE;
    const int s0 = slice * per;
    const int s1 = (s0 + per < n) ? s0 + per : n;

    u64 best = FARKEY;

    float4 r0, r1, r2, r3, rb;
    bool v = (s0 + lane) < s1;
    if (v) {
        const float4* p = (const float4*)(cf + (size_t)(s0 + lane) * 16);
        r0 = p[0]; r1 = p[1]; r2 = p[2]; r3 = p[3];
        rb = cbb[s0 + lane];
    }

    for (int cb = s0; cb < s1; cb += 64) {
        // --- cull in registers: bbox axes + 3 edge axes (exact SAT) ---
        bool pass = v;
        if (pass) {
            pass = (rb.x <= xhi) && (rb.y >= xlo) && (rb.z <= yhi) && (rb.w >= ylo);
        }
        if (pass) {
            // max of edge fn over tile rect (linear & separable); margin 1e-3
            // >> max fp error (~2e-5) -> conservative, never changes results.
            float t0m = fmaxf(r0.x * xlo, r0.x * xhi) + fmaxf(r0.w * ylo, r0.w * yhi) + r1.z;
            float t1m = fmaxf(r0.y * xlo, r0.y * xhi) + fmaxf(r1.x * ylo, r1.x * yhi) + r1.w;
            float t2m = fmaxf(r0.z * xlo, r0.z * xhi) + fmaxf(r1.y * ylo, r1.y * yhi) + r2.x;
            pass = (t0m >= -1e-3f) && (t1m >= -1e-3f) && (t2m >= -1e-3f);
        }
        u64 m = __ballot(pass);
        int cnt = __popcll(m);
        int pos = __popcll(m & ((1ull << lane) - 1ull));
        if (pass) {
            float4* dst = (float4*)(sf + (size_t)pos * 16);
            dst[0] = r0; dst[1] = r1; dst[2] = r2; dst[3] = r3;
        }
        // --- prefetch next chunk while inner loop runs ---
        int nb = cb + 64;
        v = false;
        if (nb < s1) {
            v = (nb + lane) < s1;
            if (v) {
                const float4* p = (const float4*)(cf + (size_t)(nb + lane) * 16);
                r0 = p[0]; r1 = p[1]; r2 = p[2]; r3 = p[3];
                rb = cbb[nb + lane];
            }
        }
        asm volatile("s_waitcnt lgkmcnt(0)" ::: "memory");  // ds_writes done
        // --- inner loop: bit-exact numpy scoring over compacted faces ---
        for (int j = 0; j < cnt; j++) {
            const float4* fq = (const float4*)(sf + (size_t)j * 16);
            float4 q0 = fq[0], q1 = fq[1], q2 = fq[2], q3 = fq[3];
            float t0 = __fadd_rn(__fadd_rn(__fmul_rn(xp, q0.x), __fmul_rn(yp, q0.w)), q1.z);
            float t1 = __fadd_rn(__fadd_rn(__fmul_rn(xp, q0.y), __fmul_rn(yp, q1.x)), q1.w);
            float t2 = __fadd_rn(__fadd_rn(__fmul_rn(xp, q0.z), __fmul_rn(yp, q1.y)), q2.x);
            // staged faces have ds>0 => sign(w)==sign(t): exact w>=0 test
            bool in = !(t0 < 0.0f) && !(t1 < 0.0f) && !(t2 < 0.0f);
            if (!__any(in)) continue;
            float dsf = q2.y;
            float w0 = __fdiv_rn(t0, dsf);
            float w1 = __fdiv_rn(t1, dsf);
            float w2 = __fdiv_rn(t2, dsf);
            in = in && !(w0 > 1.0f) && !(w1 > 1.0f) && !(w2 > 1.0f);
            float den = __fmul_rn(w0, q2.z);
            den = __fadd_rn(den, __fmul_rn(w1, q2.w));
            den = __fadd_rn(den, __fmul_rn(w2, q3.x));
            if (in && den > 1e-8f) {
                float zp = __fdiv_rn(1.0f, den);
                if (zp > 0.1f && zp < 100.0f) {
                    u64 key = ((u64)__float_as_uint(zp) << 32)
                            | (u64)(unsigned)__float_as_int(q3.y);
                    if (key < best) best = key;
                }
            }
        }
    }
    if (best != FARKEY)
        atomicMin(&keys[(size_t)pyi * 256 + pxi], best);
}

// ---------------------------------------------------------------------------
// Kernel 4: per-pixel epilogue — recompute exact barycentrics for the winner
// and trilinear-sample the face texture (numpy op order, bit-exact path).
// ---------------------------------------------------------------------------
__global__ __launch_bounds__(256) void epilogue(
    const u64* __restrict__ keys,
    const float* __restrict__ fdat,
    const float* __restrict__ tex,   // d_out + IMGOFF, from tex_sample
    float* __restrict__ out_img)
{
    int pix = blockIdx.x * 256 + threadIdx.x;   // 65536
    int xo = pix & 255, yo = pix >> 8;
    const float xp = (float)(2 * xo + 1 - 256) * (1.0f / 256.0f);
    const float yp = (float)(2 * yo + 1 - 256) * (1.0f / 256.0f);
    u64 m = keys[pix];
    float depth = __uint_as_float((unsigned)(m >> 32));
    float col0 = 0.f, col1 = 0.f, col2 = 0.f;
    if (depth < 100.0f) {
        int fidx = (int)(unsigned)(m & 0xFFFFFFFFu);
        const float* fd = fdat + (size_t)fidx * 16;
        float t0 = __fadd_rn(__fadd_rn(__fmul_rn(xp, fd[0]), __fmul_rn(yp, fd[3])), fd[6]);
        float t1 = __fadd_rn(__fadd_rn(__fmul_rn(xp, fd[1]), __fmul_rn(yp, fd[4])), fd[7]);
        float t2 = __fadd_rn(__fadd_rn(__fmul_rn(xp, fd[2]), __fmul_rn(yp, fd[5])), fd[8]);
        float dsf = fd[9];
        float w0 = __fdiv_rn(t0, dsf), w1 = __fdiv_rn(t1, dsf), w2 = __fdiv_rn(t2, dsf);
        float wc0 = __fdiv_rn(w0, fd[13]);
        float wc1 = __fdiv_rn(w1, fd[14]);
        float wc2 = __fdiv_rn(w2, fd[15]);
        float ssum = __fadd_rn(__fadd_rn(wc0, wc1), wc2);
        float dnm = fmaxf(ssum, 1e-8f);
        wc0 = __fdiv_rn(wc0, dnm); wc1 = __fdiv_rn(wc1, dnm); wc2 = __fdiv_rn(wc2, dnm);
        float pos0 = __fmul_rn(fminf(fmaxf(wc0, 0.f), 1.f), 2.0f);
        float pos1 = __fmul_rn(fminf(fmaxf(wc1, 0.f), 1.f), 2.0f);
        float pos2 = __fmul_rn(fminf(fmaxf(wc2, 0.f), 1.f), 2.0f);
        float lf0 = fminf(fmaxf(floorf(pos0), 0.f), 2.f);
        float lf1 = fminf(fmaxf(floorf(pos1), 0.f), 2.f);
        float lf2 = fminf(fmaxf(floorf(pos2), 0.f), 2.f);
        float fr0 = __fsub_rn(pos0, lf0), fr1 = __fsub_rn(pos1, lf1), fr2 = __fsub_rn(pos2, lf2);
        int lo0 = (int)lf0, lo1 = (int)lf1;
        int hi0 = lo0 + 1 > 2 ? 2 : lo0 + 1;
        int hi1 = lo1 + 1 > 2 ? 2 : lo1 + 1;
        const float* tbase = tex + (size_t)fidx * 81;
#pragma unroll
        for (int bits = 0; bits < 8; bits++) {
            int u0 = bits & 1, u1 = (bits >> 1) & 1, u2 = (bits >> 2) & 1;
            int i0 = u0 ? hi0 : lo0;
            int i1 = u1 ? hi1 : lo1;
            float e0 = u0 ? fr0 : __fsub_rn(1.0f, fr0);
            float e1 = u1 ? fr1 : __fsub_rn(1.0f, fr1);
            float e2 = u2 ? fr2 : __fsub_rn(1.0f, fr2);
            float wgt = __fmul_rn(__fmul_rn(e0, e1), e2);
            const float* tp = tbase + (size_t)i0 * 27 + (size_t)i1 * 9;  // k broadcast
            col0 = __fadd_rn(col0, __fmul_rn(wgt, tp[0]));
            col1 = __fadd_rn(col1, __fmul_rn(wgt, tp[1]));
            col2 = __fadd_rn(col2, __fmul_rn(wgt, tp[2]));
        }
    }
    out_img[pix]          = col0;
    out_img[65536 + pix]  = col1;
    out_img[131072 + pix] = col2;
}

extern "C" void kernel_launch(void* const* d_in, const int* in_sizes, int n_in,
                              void* d_out, int out_size, void* d_ws, size_t ws_size,
                              hipStream_t stream) {
    const float* cam   = (const float*)d_in[0];
    const float* verts = (const float*)d_in[1];
    const float* uv    = (const float*)d_in[2];
    const int*   faces = (const int*)d_in[3];
    float* out = (float*)d_out;

    char* ws = (char*)d_ws;
    u64*    keys = (u64*)(ws + OFF_KEYS);
    int*    fcnt = (int*)(ws + OFF_FCNT);
    float*  fdat = (float*)(ws + OFF_FDAT);
    float*  cf   = (float*)(ws + OFF_CF);
    float4* cbb  = (float4*)(ws + OFF_CBB);

    float* out_img = out;            // 3*256*256
    float* out_tex = out + IMGOFF;   // NF*81

    hipLaunchKernelGGL(init_ws, dim3(256), dim3(256), 0, stream, keys, fcnt);
    hipLaunchKernelGGL(face_prep, dim3((NF + 255) / 256), dim3(256), 0, stream,
                       cam, verts, faces, fdat, cf, cbb, fcnt);
    hipLaunchKernelGGL(tex_sample, dim3((NF * 9 + 255) / 256), dim3(256), 0, stream,
                       cam, verts, faces, uv, out_tex);
    hipLaunchKernelGGL(raster_min, dim3(4096), dim3(256), 0, stream,
                       cf, cbb, fcnt, keys);
    hipLaunchKernelGGL(epilogue, dim3(256), dim3(256), 0, stream,
                       keys, fdat, out_tex, out_img);
}